// Round 13
// baseline (402.313 us; speedup 1.0000x reference)
//
#include <hip/hip_runtime.h>
#include <hip/hip_fp16.h>
#include <math.h>

// GAT 3-layer forward for MI355X.
// R12: degree-sorted node permutation for agg kernels. aggq's wave loop
// runs to max-degree-of-4-quarters (~25% masked waste at Poisson(17));
// processing perm[]-adjacent (degree-equal) nodes removes it. Per-node
// arithmetic unchanged (same CSR segment/order) -> bit-identical results.
// Everything else = R11: fp16 h gathers, depth-4/unroll-2 agg pipeline,
// padded csr, two-level CSR build, gemm0, [agg+gemm] x2 fused, agg_final.

#define NEG_SLOPE 0.2f
#define L1_CHUNK 4096

// ---------------- two-level CSR build ----------------

__global__ __launch_bounds__(256) void k_l1hist(
    const int* __restrict__ idx, int* __restrict__ ghist, int E, int etot) {
    __shared__ int h[256];
    const int t = threadIdx.x;
    h[t] = 0;
    __syncthreads();
    const int base = blockIdx.x * L1_CHUNK;
    for (int i = t; i < L1_CHUNK; i += 256) {
        int e = base + i;
        if (e >= etot) break;
        int dst = (e < E) ? idx[E + e] : (e - E);
        atomicAdd(&h[dst >> 8], 1);
    }
    __syncthreads();
    if (h[t]) atomicAdd(&ghist[t], h[t]);
}

__global__ __launch_bounds__(256) void k_scan256(
    const int* __restrict__ ghist, int* __restrict__ goff, int* __restrict__ gcur) {
    __shared__ int sc[256];
    const int t = threadIdx.x;
    int v = ghist[t];
    sc[t] = v;
    __syncthreads();
    for (int o = 1; o < 256; o <<= 1) {
        int x = (t >= o) ? sc[t - o] : 0;
        __syncthreads();
        sc[t] += x;
        __syncthreads();
    }
    int excl = sc[t] - v;
    goff[t] = excl;
    gcur[t] = excl;
    if (t == 255) goff[256] = sc[255];
}

__global__ __launch_bounds__(256) void k_l1scatter(
    const int* __restrict__ idx, int* __restrict__ gcur,
    unsigned long long* __restrict__ buf, int E, int etot) {
    __shared__ int h[256];
    __shared__ int lbase[256];
    const int t = threadIdx.x;
    h[t] = 0;
    __syncthreads();
    const int base = blockIdx.x * L1_CHUNK;
    for (int i = t; i < L1_CHUNK; i += 256) {
        int e = base + i;
        if (e >= etot) break;
        int dst = (e < E) ? idx[E + e] : (e - E);
        atomicAdd(&h[dst >> 8], 1);
    }
    __syncthreads();
    lbase[t] = h[t] ? atomicAdd(&gcur[t], h[t]) : 0;
    __syncthreads();
    h[t] = lbase[t];
    __syncthreads();
    for (int i = t; i < L1_CHUNK; i += 256) {
        int e = base + i;
        if (e >= etot) break;
        int dst, src;
        if (e < E) { dst = idx[E + e]; src = idx[e]; }
        else       { dst = src = e - E; }
        int pos = atomicAdd(&h[dst >> 8], 1);
        buf[pos] = ((unsigned long long)(unsigned)dst << 32) | (unsigned)src;
    }
}

// per-bucket exact-dst counting sort -> off[], csr[]; also degree histogram
__global__ __launch_bounds__(256) void k_l2build(
    const unsigned long long* __restrict__ buf, const int* __restrict__ goff,
    int* __restrict__ off, int* __restrict__ csr, int* __restrict__ dhist,
    int n, int etot) {
    __shared__ int sc[256];
    __shared__ int lcur[256];
    const int b = blockIdx.x, t = threadIdx.x;
    const int lo = goff[b], hi = goff[b + 1];
    sc[t] = 0;
    __syncthreads();
    for (int p = lo + t; p < hi; p += 256) {
        int dst = (int)(buf[p] >> 32);
        atomicAdd(&sc[dst & 255], 1);
    }
    __syncthreads();
    int v = sc[t];
    __syncthreads();
    sc[t] = v;
    __syncthreads();
    for (int o = 1; o < 256; o <<= 1) {
        int x = (t >= o) ? sc[t - o] : 0;
        __syncthreads();
        sc[t] += x;
        __syncthreads();
    }
    int excl = sc[t] - v;
    const int d = b * 256 + t;
    if (d < n) {
        off[d] = lo + excl;
        atomicAdd(&dhist[v > 255 ? 255 : v], 1);   // degree histogram
    }
    lcur[t] = lo + excl;
    __syncthreads();
    for (int p = lo + t; p < hi; p += 256) {
        unsigned long long e = buf[p];
        int dst = (int)(e >> 32);
        int src = (int)(e & 0xffffffffu);
        int pos = atomicAdd(&lcur[dst & 255], 1);
        csr[pos] = src;
    }
    if (b == 0 && t == 0) off[n] = etot;
    if (b == 0 && t < 8) csr[etot + t] = 0;   // prefetch pad (safe src idx)
}

// 1-block exclusive scan of degree histogram -> dcur
__global__ __launch_bounds__(256) void k_degscan(
    const int* __restrict__ dhist, int* __restrict__ dcur) {
    __shared__ int sc[256];
    const int t = threadIdx.x;
    int v = dhist[t];
    sc[t] = v;
    __syncthreads();
    for (int o = 1; o < 256; o <<= 1) {
        int x = (t >= o) ? sc[t - o] : 0;
        __syncthreads();
        sc[t] += x;
        __syncthreads();
    }
    dcur[t] = sc[t] - v;
}

// build degree-sorted permutation (LDS-staged; ~40 global atomics/block)
__global__ __launch_bounds__(256) void k_permscatter(
    const int* __restrict__ off, int* __restrict__ dcur,
    int* __restrict__ perm, int n) {
    __shared__ int h[256];
    __shared__ int cur[256];
    const int t = threadIdx.x;
    h[t] = 0;
    __syncthreads();
    const int d = blockIdx.x * 256 + t;
    int bin = -1;
    if (d < n) {
        int deg = off[d + 1] - off[d];
        bin = deg > 255 ? 255 : deg;
        atomicAdd(&h[bin], 1);
    }
    __syncthreads();
    cur[t] = h[t] ? atomicAdd(&dcur[t], h[t]) : 0;
    __syncthreads();
    h[t] = cur[t];
    __syncthreads();
    if (d < n) {
        int pos = atomicAdd(&h[bin], 1);
        perm[pos] = d;
    }
}

// ---------------- compute ----------------

// Quarter-per-node aggregate over fp16 h rows, unroll x2, depth-4 pipeline.
// 16 lanes own all 64 cols of `node` (lane c4 -> cols 4c4..4c4+3, 8B load).
// csr is zero-padded by 8 so stage loads need no clamp; p freezes at >=e.
template <int H>
__device__ __forceinline__ float4 aggq(
    const __half* __restrict__ h, const float* __restrict__ asb,
    const float* __restrict__ adb, const int* __restrict__ off,
    const int* __restrict__ csr, int node, int c4, int n) {
    const int head = (H == 1) ? 0 : (c4 >> 2);
    float den = 0.f;
    float4 acc = make_float4(0.f, 0.f, 0.f, 0.f);
    int p = 0, e = 0;
    float adn = 0.f;
    if (node < n) {
        p = off[node];
        e = off[node + 1];
        adn = adb[node * H + head];
    }
    int s0 = csr[p], s1 = csr[p + 1], s2 = csr[p + 2], s3 = csr[p + 3];
    float a0 = asb[s0 * H + head];
    float a1 = asb[s1 * H + head];
    uint2 v0 = *(const uint2*)(h + (size_t)s0 * 64 + c4 * 4);
    uint2 v1 = *(const uint2*)(h + (size_t)s1 * 64 + c4 * 4);
    while (__any(p < e)) {
        const bool q0 = p < e;
        const bool q1 = (p + 1) < e;
        const int s4 = csr[p + 4];
        const int s5 = csr[p + 5];
        const float a2 = asb[s2 * H + head];
        const float a3 = asb[s3 * H + head];
        const uint2 v2 = *(const uint2*)(h + (size_t)s2 * 64 + c4 * 4);
        const uint2 v3 = *(const uint2*)(h + (size_t)s3 * 64 + c4 * 4);
        {
            float ev = a0 + adn;
            ev = ev > 0.f ? ev : NEG_SLOPE * ev;
            const float wv = q0 ? __expf(ev) : 0.f;
            const float2 f01 = __half22float2(*(const __half2*)&v0.x);
            const float2 f23 = __half22float2(*(const __half2*)&v0.y);
            den += wv;
            acc.x = fmaf(wv, f01.x, acc.x);
            acc.y = fmaf(wv, f01.y, acc.y);
            acc.z = fmaf(wv, f23.x, acc.z);
            acc.w = fmaf(wv, f23.y, acc.w);
        }
        {
            float ev = a1 + adn;
            ev = ev > 0.f ? ev : NEG_SLOPE * ev;
            const float wv = q1 ? __expf(ev) : 0.f;
            const float2 f01 = __half22float2(*(const __half2*)&v1.x);
            const float2 f23 = __half22float2(*(const __half2*)&v1.y);
            den += wv;
            acc.x = fmaf(wv, f01.x, acc.x);
            acc.y = fmaf(wv, f01.y, acc.y);
            acc.z = fmaf(wv, f23.x, acc.z);
            acc.w = fmaf(wv, f23.y, acc.w);
        }
        p = q0 ? p + 2 : p;
        s0 = s2; s1 = s3; s2 = s4; s3 = s5;
        a0 = a2; a1 = a3;
        v0 = v2; v1 = v3;
    }
    const float inv = 1.f / (den + 1e-16f);
    return make_float4(acc.x * inv, acc.y * inv, acc.z * inv, acc.w * inv);
}

// Layer-0 GEMM: h = x @ W (K=128) + logits. Block = 16 nodes, wave = 4.
template <int K, int H, int F>
__global__ __launch_bounds__(256) void k_gemm_alpha(
    const float* __restrict__ x, const float* __restrict__ W,
    const float* __restrict__ a_s, const float* __restrict__ a_d,
    __half* __restrict__ h, float* __restrict__ as_o, float* __restrict__ ad_o,
    int n) {
    __shared__ float xs[16][K];
    const int tid = threadIdx.x;
    const int base = blockIdx.x * 16;
    int rows = n - base; if (rows > 16) rows = 16;
    const int kv = K / 4;
    for (int i = tid; i < rows * kv; i += 256) {
        int r = i / kv, c = i - r * kv;
        ((float4*)&xs[r][0])[c] = ((const float4*)(x + (size_t)(base + r) * K))[c];
    }
    __syncthreads();
    const int w = tid >> 6, lane = tid & 63;
    const int node0 = base + w * 4;
    float acc0 = 0.f, acc1 = 0.f, acc2 = 0.f, acc3 = 0.f;
    #pragma unroll 4
    for (int k = 0; k < K; ++k) {
        float wv = W[k * 64 + lane];
        acc0 = fmaf(xs[w * 4 + 0][k], wv, acc0);
        acc1 = fmaf(xs[w * 4 + 1][k], wv, acc1);
        acc2 = fmaf(xs[w * 4 + 2][k], wv, acc2);
        acc3 = fmaf(xs[w * 4 + 3][k], wv, acc3);
    }
    const int head = (H == 1) ? 0 : (lane >> 4);
    const int f = (H == 1) ? lane : (lane & (F - 1));
    const float asv = a_s[head * F + f];
    const float adv = a_d[head * F + f];
    float accs[4] = {acc0, acc1, acc2, acc3};
    #pragma unroll
    for (int j = 0; j < 4; ++j) {
        int node = node0 + j;
        if (node >= n) break;
        h[(size_t)node * 64 + lane] = __float2half_rn(accs[j]);
        float vs = accs[j] * asv;
        float vd = accs[j] * adv;
        #pragma unroll
        for (int o = F >> 1; o > 0; o >>= 1) {
            vs += __shfl_xor(vs, o);
            vd += __shfl_xor(vd, o);
        }
        if (f == 0) {
            as_o[node * H + head] = vs;
            ad_o[node * H + head] = vd;
        }
    }
}

// Fused agg(layer l) -> +bias -> ELU -> gemm(layer l+1) + logits.
// Nodes taken through degree-sorted perm: quarter q of wave w processes
// perm[base + w*4 + q]; GEMM outputs written at permuted node rows.
template <int HA, int HG, int FG>
__global__ __launch_bounds__(256) void k_agg_gemm(
    const __half* __restrict__ h_in, const float* __restrict__ asb_in,
    const float* __restrict__ adb_in, const int* __restrict__ off,
    const int* __restrict__ csr, const int* __restrict__ perm,
    const float* __restrict__ bias, const float* __restrict__ W,
    const float* __restrict__ a_s, const float* __restrict__ a_d,
    __half* __restrict__ h_out, float* __restrict__ asb_out,
    float* __restrict__ adb_out, int n) {
    __shared__ float xs[16][64];
    const int tid = threadIdx.x;
    const int w = tid >> 6, lane = tid & 63;
    const int q = lane >> 4, c4 = lane & 15;
    const int base = blockIdx.x * 16;
    const int gA = base + w * 4 + q;
    const int nodeA = (gA < n) ? perm[gA] : n;
    float4 r = aggq<HA>(h_in, asb_in, adb_in, off, csr, nodeA, c4, n);
    if (nodeA < n) {
        const float4 bv = *(const float4*)(bias + c4 * 4);
        r.x += bv.x; r.y += bv.y; r.z += bv.z; r.w += bv.w;
        r.x = r.x > 0.f ? r.x : expm1f(r.x);
        r.y = r.y > 0.f ? r.y : expm1f(r.y);
        r.z = r.z > 0.f ? r.z : expm1f(r.z);
        r.w = r.w > 0.f ? r.w : expm1f(r.w);
        *(float4*)&xs[w * 4 + q][c4 * 4] = r;
    }
    __syncthreads();
    float acc0 = 0.f, acc1 = 0.f, acc2 = 0.f, acc3 = 0.f;
    #pragma unroll 4
    for (int k = 0; k < 64; ++k) {
        float wv = W[k * 64 + lane];
        acc0 = fmaf(xs[w * 4 + 0][k], wv, acc0);
        acc1 = fmaf(xs[w * 4 + 1][k], wv, acc1);
        acc2 = fmaf(xs[w * 4 + 2][k], wv, acc2);
        acc3 = fmaf(xs[w * 4 + 3][k], wv, acc3);
    }
    const int head = (HG == 1) ? 0 : (lane >> 4);
    const int f = (HG == 1) ? lane : (lane & (FG - 1));
    const float asv = a_s[head * FG + f];
    const float adv = a_d[head * FG + f];
    float accs[4] = {acc0, acc1, acc2, acc3};
    #pragma unroll
    for (int j = 0; j < 4; ++j) {
        const int gj = base + w * 4 + j;
        if (gj >= n) break;
        const int node = perm[gj];
        h_out[(size_t)node * 64 + lane] = __float2half_rn(accs[j]);
        float vs = accs[j] * asv;
        float vd = accs[j] * adv;
        #pragma unroll
        for (int o = FG >> 1; o > 0; o >>= 1) {
            vs += __shfl_xor(vs, o);
            vd += __shfl_xor(vd, o);
        }
        if (f == 0) {
            asb_out[node * HG + head] = vs;
            adb_out[node * HG + head] = vd;
        }
    }
}

// Final aggregate (layer 2, H=1, no ELU) -> fp32 d_out. Quarter per node.
__global__ __launch_bounds__(256) void k_agg_final(
    const __half* __restrict__ h, const float* __restrict__ asb,
    const float* __restrict__ adb, const int* __restrict__ off,
    const int* __restrict__ csr, const int* __restrict__ perm,
    const float* __restrict__ bias, float* __restrict__ out, int n) {
    const int tid = threadIdx.x;
    const int w = tid >> 6, lane = tid & 63;
    const int q = lane >> 4, c4 = lane & 15;
    const int g = blockIdx.x * 16 + w * 4 + q;
    const int node = (g < n) ? perm[g] : n;
    float4 r = aggq<1>(h, asb, adb, off, csr, node, c4, n);
    if (node < n) {
        const float4 bv = *(const float4*)(bias + c4 * 4);
        r.x += bv.x; r.y += bv.y; r.z += bv.z; r.w += bv.w;
        *(float4*)(out + (size_t)node * 64 + c4 * 4) = r;
    }
}

// ---------------- launch ----------------

extern "C" void kernel_launch(void* const* d_in, const int* in_sizes, int n_in,
                              void* d_out, int out_size, void* d_ws, size_t ws_size,
                              hipStream_t stream) {
    const float* x   = (const float*)d_in[0];
    const int*   idx = (const int*)d_in[1];
    const float* W0  = (const float*)d_in[2];
    const float* as0 = (const float*)d_in[3];
    const float* ad0 = (const float*)d_in[4];
    const float* b0  = (const float*)d_in[5];
    const float* W1  = (const float*)d_in[6];
    const float* as1 = (const float*)d_in[7];
    const float* ad1 = (const float*)d_in[8];
    const float* b1  = (const float*)d_in[9];
    const float* W2  = (const float*)d_in[10];
    const float* as2 = (const float*)d_in[11];
    const float* ad2 = (const float*)d_in[12];
    const float* b2  = (const float*)d_in[13];
    float* out = (float*)d_out;

    const int n    = in_sizes[0] / 128;   // 50000
    const int E    = in_sizes[1] / 2;     // 800000
    const int etot = E + n;

    char* p = (char*)d_ws;
    auto alloc = [&](size_t bytes) {
        char* r = p;
        p += (bytes + 255) & ~(size_t)255;
        return r;
    };
    int*    off   = (int*)alloc((size_t)(n + 1) * 4);
    int*    csr   = (int*)alloc((size_t)(etot + 8) * 4);   // +8 prefetch pad
    int*    ghist = (int*)alloc(256 * 4);                  // ghist+dhist:
    int*    dhist = (int*)alloc(256 * 4);                  // contiguous
    int*    goff  = (int*)alloc(257 * 4);
    int*    gcur  = (int*)alloc(256 * 4);
    int*    dcur  = (int*)alloc(256 * 4);
    int*    perm  = (int*)alloc((size_t)n * 4);
    float*  asbA  = (float*)alloc((size_t)n * 4 * 4);
    float*  adbA  = (float*)alloc((size_t)n * 4 * 4);
    float*  asbB  = (float*)alloc((size_t)n * 4 * 4);
    float*  adbB  = (float*)alloc((size_t)n * 4 * 4);
    __half* hA    = (__half*)alloc((size_t)n * 64 * 2);
    __half* hB    = (__half*)alloc((size_t)n * 64 * 2);
    unsigned long long* buf = (unsigned long long*)alloc((size_t)etot * 8);

    const int nb_l1 = (etot + L1_CHUNK - 1) / L1_CHUNK;  // 208
    const int nb_l2 = (n + 255) / 256;                   // 196
    const int nb_g  = (n + 15) / 16;                     // 3125

    // CSR build + degree-sorted permutation
    hipMemsetAsync(ghist, 0, 2 * 256 * 4, stream);       // ghist + dhist
    k_l1hist<<<nb_l1, 256, 0, stream>>>(idx, ghist, E, etot);
    k_scan256<<<1, 256, 0, stream>>>(ghist, goff, gcur);
    k_l1scatter<<<nb_l1, 256, 0, stream>>>(idx, gcur, buf, E, etot);
    k_l2build<<<nb_l2, 256, 0, stream>>>(buf, goff, off, csr, dhist, n, etot);
    k_degscan<<<1, 256, 0, stream>>>(dhist, dcur);
    k_permscatter<<<nb_l2, 256, 0, stream>>>(off, dcur, perm, n);

    // layer 0 GEMM: x(128) -> hA(fp16), logits A
    k_gemm_alpha<128, 4, 16><<<nb_g, 256, 0, stream>>>(x, W0, as0, ad0, hA, asbA, adbA, n);
    // agg0 (+b0, ELU) -> gemm1 -> hB(fp16), logits B
    k_agg_gemm<4, 4, 16><<<nb_g, 256, 0, stream>>>(hA, asbA, adbA, off, csr, perm, b0,
                                                   W1, as1, ad1, hB, asbB, adbB, n);
    // agg1 (+b1, ELU) -> gemm2 -> hA(fp16), logits A
    k_agg_gemm<4, 1, 64><<<nb_g, 256, 0, stream>>>(hB, asbB, adbB, off, csr, perm, b1,
                                                   W2, as2, ad2, hA, asbA, adbA, n);
    // agg2 (+b2) -> fp32 out
    k_agg_final<<<nb_g, 256, 0, stream>>>(hA, asbA, adbA, off, csr, perm, b2, out, n);
}

// Round 14
// 264.653 us; speedup vs baseline: 1.5202x; 1.5202x over previous
//
#include <hip/hip_runtime.h>
#include <hip/hip_fp16.h>
#include <math.h>

// GAT 3-layer forward for MI355X.
// R13: fix R12's regression - the degree histogram in k_l2build used one
// GLOBAL atomic per node onto ~20 hot bins (Poisson degrees) -> ~150us of
// atomic serialization. Now LDS-staged per block + one flush per nonzero
// bin (Guideline 12). Rest = R12: degree-sorted perm for agg, fp16 h
// gathers, depth-4/unroll-2 agg pipeline, padded csr, two-level CSR build,
// gemm0, [agg+gemm] x2 fused, agg_final.

#define NEG_SLOPE 0.2f
#define L1_CHUNK 4096

// ---------------- two-level CSR build ----------------

__global__ __launch_bounds__(256) void k_l1hist(
    const int* __restrict__ idx, int* __restrict__ ghist, int E, int etot) {
    __shared__ int h[256];
    const int t = threadIdx.x;
    h[t] = 0;
    __syncthreads();
    const int base = blockIdx.x * L1_CHUNK;
    for (int i = t; i < L1_CHUNK; i += 256) {
        int e = base + i;
        if (e >= etot) break;
        int dst = (e < E) ? idx[E + e] : (e - E);
        atomicAdd(&h[dst >> 8], 1);
    }
    __syncthreads();
    if (h[t]) atomicAdd(&ghist[t], h[t]);
}

__global__ __launch_bounds__(256) void k_scan256(
    const int* __restrict__ ghist, int* __restrict__ goff, int* __restrict__ gcur) {
    __shared__ int sc[256];
    const int t = threadIdx.x;
    int v = ghist[t];
    sc[t] = v;
    __syncthreads();
    for (int o = 1; o < 256; o <<= 1) {
        int x = (t >= o) ? sc[t - o] : 0;
        __syncthreads();
        sc[t] += x;
        __syncthreads();
    }
    int excl = sc[t] - v;
    goff[t] = excl;
    gcur[t] = excl;
    if (t == 255) goff[256] = sc[255];
}

__global__ __launch_bounds__(256) void k_l1scatter(
    const int* __restrict__ idx, int* __restrict__ gcur,
    unsigned long long* __restrict__ buf, int E, int etot) {
    __shared__ int h[256];
    __shared__ int lbase[256];
    const int t = threadIdx.x;
    h[t] = 0;
    __syncthreads();
    const int base = blockIdx.x * L1_CHUNK;
    for (int i = t; i < L1_CHUNK; i += 256) {
        int e = base + i;
        if (e >= etot) break;
        int dst = (e < E) ? idx[E + e] : (e - E);
        atomicAdd(&h[dst >> 8], 1);
    }
    __syncthreads();
    lbase[t] = h[t] ? atomicAdd(&gcur[t], h[t]) : 0;
    __syncthreads();
    h[t] = lbase[t];
    __syncthreads();
    for (int i = t; i < L1_CHUNK; i += 256) {
        int e = base + i;
        if (e >= etot) break;
        int dst, src;
        if (e < E) { dst = idx[E + e]; src = idx[e]; }
        else       { dst = src = e - E; }
        int pos = atomicAdd(&h[dst >> 8], 1);
        buf[pos] = ((unsigned long long)(unsigned)dst << 32) | (unsigned)src;
    }
}

// per-bucket exact-dst counting sort -> off[], csr[]; LDS-staged deg hist
__global__ __launch_bounds__(256) void k_l2build(
    const unsigned long long* __restrict__ buf, const int* __restrict__ goff,
    int* __restrict__ off, int* __restrict__ csr, int* __restrict__ dhist,
    int n, int etot) {
    __shared__ int sc[256];
    __shared__ int lcur[256];
    __shared__ int dh[256];
    const int b = blockIdx.x, t = threadIdx.x;
    const int lo = goff[b], hi = goff[b + 1];
    sc[t] = 0;
    dh[t] = 0;
    __syncthreads();
    for (int p = lo + t; p < hi; p += 256) {
        int dst = (int)(buf[p] >> 32);
        atomicAdd(&sc[dst & 255], 1);
    }
    __syncthreads();
    int v = sc[t];
    __syncthreads();
    sc[t] = v;
    __syncthreads();
    for (int o = 1; o < 256; o <<= 1) {
        int x = (t >= o) ? sc[t - o] : 0;
        __syncthreads();
        sc[t] += x;
        __syncthreads();
    }
    int excl = sc[t] - v;
    const int d = b * 256 + t;
    if (d < n) {
        off[d] = lo + excl;
        atomicAdd(&dh[v > 255 ? 255 : v], 1);   // LDS degree histogram
    }
    lcur[t] = lo + excl;
    __syncthreads();
    for (int p = lo + t; p < hi; p += 256) {
        unsigned long long e = buf[p];
        int dst = (int)(e >> 32);
        int src = (int)(e & 0xffffffffu);
        int pos = atomicAdd(&lcur[dst & 255], 1);
        csr[pos] = src;
    }
    if (dh[t]) atomicAdd(&dhist[t], dh[t]);     // one flush per nonzero bin
    if (b == 0 && t == 0) off[n] = etot;
    if (b == 0 && t < 8) csr[etot + t] = 0;     // prefetch pad
}

// 1-block exclusive scan of degree histogram -> dcur
__global__ __launch_bounds__(256) void k_degscan(
    const int* __restrict__ dhist, int* __restrict__ dcur) {
    __shared__ int sc[256];
    const int t = threadIdx.x;
    int v = dhist[t];
    sc[t] = v;
    __syncthreads();
    for (int o = 1; o < 256; o <<= 1) {
        int x = (t >= o) ? sc[t - o] : 0;
        __syncthreads();
        sc[t] += x;
        __syncthreads();
    }
    dcur[t] = sc[t] - v;
}

// build degree-sorted permutation (LDS-staged; ~30 global atomics/block)
__global__ __launch_bounds__(256) void k_permscatter(
    const int* __restrict__ off, int* __restrict__ dcur,
    int* __restrict__ perm, int n) {
    __shared__ int h[256];
    __shared__ int cur[256];
    const int t = threadIdx.x;
    h[t] = 0;
    __syncthreads();
    const int d = blockIdx.x * 256 + t;
    int bin = -1;
    if (d < n) {
        int deg = off[d + 1] - off[d];
        bin = deg > 255 ? 255 : deg;
        atomicAdd(&h[bin], 1);
    }
    __syncthreads();
    cur[t] = h[t] ? atomicAdd(&dcur[t], h[t]) : 0;
    __syncthreads();
    h[t] = cur[t];
    __syncthreads();
    if (d < n) {
        int pos = atomicAdd(&h[bin], 1);
        perm[pos] = d;
    }
}

// ---------------- compute ----------------

// Quarter-per-node aggregate over fp16 h rows, unroll x2, depth-4 pipeline.
// 16 lanes own all 64 cols of `node` (lane c4 -> cols 4c4..4c4+3, 8B load).
// csr is zero-padded by 8 so stage loads need no clamp; p freezes at >=e.
template <int H>
__device__ __forceinline__ float4 aggq(
    const __half* __restrict__ h, const float* __restrict__ asb,
    const float* __restrict__ adb, const int* __restrict__ off,
    const int* __restrict__ csr, int node, int c4, int n) {
    const int head = (H == 1) ? 0 : (c4 >> 2);
    float den = 0.f;
    float4 acc = make_float4(0.f, 0.f, 0.f, 0.f);
    int p = 0, e = 0;
    float adn = 0.f;
    if (node < n) {
        p = off[node];
        e = off[node + 1];
        adn = adb[node * H + head];
    }
    int s0 = csr[p], s1 = csr[p + 1], s2 = csr[p + 2], s3 = csr[p + 3];
    float a0 = asb[s0 * H + head];
    float a1 = asb[s1 * H + head];
    uint2 v0 = *(const uint2*)(h + (size_t)s0 * 64 + c4 * 4);
    uint2 v1 = *(const uint2*)(h + (size_t)s1 * 64 + c4 * 4);
    while (__any(p < e)) {
        const bool q0 = p < e;
        const bool q1 = (p + 1) < e;
        const int s4 = csr[p + 4];
        const int s5 = csr[p + 5];
        const float a2 = asb[s2 * H + head];
        const float a3 = asb[s3 * H + head];
        const uint2 v2 = *(const uint2*)(h + (size_t)s2 * 64 + c4 * 4);
        const uint2 v3 = *(const uint2*)(h + (size_t)s3 * 64 + c4 * 4);
        {
            float ev = a0 + adn;
            ev = ev > 0.f ? ev : NEG_SLOPE * ev;
            const float wv = q0 ? __expf(ev) : 0.f;
            const float2 f01 = __half22float2(*(const __half2*)&v0.x);
            const float2 f23 = __half22float2(*(const __half2*)&v0.y);
            den += wv;
            acc.x = fmaf(wv, f01.x, acc.x);
            acc.y = fmaf(wv, f01.y, acc.y);
            acc.z = fmaf(wv, f23.x, acc.z);
            acc.w = fmaf(wv, f23.y, acc.w);
        }
        {
            float ev = a1 + adn;
            ev = ev > 0.f ? ev : NEG_SLOPE * ev;
            const float wv = q1 ? __expf(ev) : 0.f;
            const float2 f01 = __half22float2(*(const __half2*)&v1.x);
            const float2 f23 = __half22float2(*(const __half2*)&v1.y);
            den += wv;
            acc.x = fmaf(wv, f01.x, acc.x);
            acc.y = fmaf(wv, f01.y, acc.y);
            acc.z = fmaf(wv, f23.x, acc.z);
            acc.w = fmaf(wv, f23.y, acc.w);
        }
        p = q0 ? p + 2 : p;
        s0 = s2; s1 = s3; s2 = s4; s3 = s5;
        a0 = a2; a1 = a3;
        v0 = v2; v1 = v3;
    }
    const float inv = 1.f / (den + 1e-16f);
    return make_float4(acc.x * inv, acc.y * inv, acc.z * inv, acc.w * inv);
}

// Layer-0 GEMM: h = x @ W (K=128) + logits. Block = 16 nodes, wave = 4.
template <int K, int H, int F>
__global__ __launch_bounds__(256) void k_gemm_alpha(
    const float* __restrict__ x, const float* __restrict__ W,
    const float* __restrict__ a_s, const float* __restrict__ a_d,
    __half* __restrict__ h, float* __restrict__ as_o, float* __restrict__ ad_o,
    int n) {
    __shared__ float xs[16][K];
    const int tid = threadIdx.x;
    const int base = blockIdx.x * 16;
    int rows = n - base; if (rows > 16) rows = 16;
    const int kv = K / 4;
    for (int i = tid; i < rows * kv; i += 256) {
        int r = i / kv, c = i - r * kv;
        ((float4*)&xs[r][0])[c] = ((const float4*)(x + (size_t)(base + r) * K))[c];
    }
    __syncthreads();
    const int w = tid >> 6, lane = tid & 63;
    const int node0 = base + w * 4;
    float acc0 = 0.f, acc1 = 0.f, acc2 = 0.f, acc3 = 0.f;
    #pragma unroll 4
    for (int k = 0; k < K; ++k) {
        float wv = W[k * 64 + lane];
        acc0 = fmaf(xs[w * 4 + 0][k], wv, acc0);
        acc1 = fmaf(xs[w * 4 + 1][k], wv, acc1);
        acc2 = fmaf(xs[w * 4 + 2][k], wv, acc2);
        acc3 = fmaf(xs[w * 4 + 3][k], wv, acc3);
    }
    const int head = (H == 1) ? 0 : (lane >> 4);
    const int f = (H == 1) ? lane : (lane & (F - 1));
    const float asv = a_s[head * F + f];
    const float adv = a_d[head * F + f];
    float accs[4] = {acc0, acc1, acc2, acc3};
    #pragma unroll
    for (int j = 0; j < 4; ++j) {
        int node = node0 + j;
        if (node >= n) break;
        h[(size_t)node * 64 + lane] = __float2half_rn(accs[j]);
        float vs = accs[j] * asv;
        float vd = accs[j] * adv;
        #pragma unroll
        for (int o = F >> 1; o > 0; o >>= 1) {
            vs += __shfl_xor(vs, o);
            vd += __shfl_xor(vd, o);
        }
        if (f == 0) {
            as_o[node * H + head] = vs;
            ad_o[node * H + head] = vd;
        }
    }
}

// Fused agg(layer l) -> +bias -> ELU -> gemm(layer l+1) + logits.
// Nodes taken through degree-sorted perm: quarter q of wave w processes
// perm[base + w*4 + q]; GEMM outputs written at permuted node rows.
template <int HA, int HG, int FG>
__global__ __launch_bounds__(256) void k_agg_gemm(
    const __half* __restrict__ h_in, const float* __restrict__ asb_in,
    const float* __restrict__ adb_in, const int* __restrict__ off,
    const int* __restrict__ csr, const int* __restrict__ perm,
    const float* __restrict__ bias, const float* __restrict__ W,
    const float* __restrict__ a_s, const float* __restrict__ a_d,
    __half* __restrict__ h_out, float* __restrict__ asb_out,
    float* __restrict__ adb_out, int n) {
    __shared__ float xs[16][64];
    const int tid = threadIdx.x;
    const int w = tid >> 6, lane = tid & 63;
    const int q = lane >> 4, c4 = lane & 15;
    const int base = blockIdx.x * 16;
    const int gA = base + w * 4 + q;
    const int nodeA = (gA < n) ? perm[gA] : n;
    float4 r = aggq<HA>(h_in, asb_in, adb_in, off, csr, nodeA, c4, n);
    if (nodeA < n) {
        const float4 bv = *(const float4*)(bias + c4 * 4);
        r.x += bv.x; r.y += bv.y; r.z += bv.z; r.w += bv.w;
        r.x = r.x > 0.f ? r.x : expm1f(r.x);
        r.y = r.y > 0.f ? r.y : expm1f(r.y);
        r.z = r.z > 0.f ? r.z : expm1f(r.z);
        r.w = r.w > 0.f ? r.w : expm1f(r.w);
        *(float4*)&xs[w * 4 + q][c4 * 4] = r;
    }
    __syncthreads();
    float acc0 = 0.f, acc1 = 0.f, acc2 = 0.f, acc3 = 0.f;
    #pragma unroll 4
    for (int k = 0; k < 64; ++k) {
        float wv = W[k * 64 + lane];
        acc0 = fmaf(xs[w * 4 + 0][k], wv, acc0);
        acc1 = fmaf(xs[w * 4 + 1][k], wv, acc1);
        acc2 = fmaf(xs[w * 4 + 2][k], wv, acc2);
        acc3 = fmaf(xs[w * 4 + 3][k], wv, acc3);
    }
    const int head = (HG == 1) ? 0 : (lane >> 4);
    const int f = (HG == 1) ? lane : (lane & (FG - 1));
    const float asv = a_s[head * FG + f];
    const float adv = a_d[head * FG + f];
    float accs[4] = {acc0, acc1, acc2, acc3};
    #pragma unroll
    for (int j = 0; j < 4; ++j) {
        const int gj = base + w * 4 + j;
        if (gj >= n) break;
        const int node = perm[gj];
        h_out[(size_t)node * 64 + lane] = __float2half_rn(accs[j]);
        float vs = accs[j] * asv;
        float vd = accs[j] * adv;
        #pragma unroll
        for (int o = FG >> 1; o > 0; o >>= 1) {
            vs += __shfl_xor(vs, o);
            vd += __shfl_xor(vd, o);
        }
        if (f == 0) {
            asb_out[node * HG + head] = vs;
            adb_out[node * HG + head] = vd;
        }
    }
}

// Final aggregate (layer 2, H=1, no ELU) -> fp32 d_out. Quarter per node.
__global__ __launch_bounds__(256) void k_agg_final(
    const __half* __restrict__ h, const float* __restrict__ asb,
    const float* __restrict__ adb, const int* __restrict__ off,
    const int* __restrict__ csr, const int* __restrict__ perm,
    const float* __restrict__ bias, float* __restrict__ out, int n) {
    const int tid = threadIdx.x;
    const int w = tid >> 6, lane = tid & 63;
    const int q = lane >> 4, c4 = lane & 15;
    const int g = blockIdx.x * 16 + w * 4 + q;
    const int node = (g < n) ? perm[g] : n;
    float4 r = aggq<1>(h, asb, adb, off, csr, node, c4, n);
    if (node < n) {
        const float4 bv = *(const float4*)(bias + c4 * 4);
        r.x += bv.x; r.y += bv.y; r.z += bv.z; r.w += bv.w;
        *(float4*)(out + (size_t)node * 64 + c4 * 4) = r;
    }
}

// ---------------- launch ----------------

extern "C" void kernel_launch(void* const* d_in, const int* in_sizes, int n_in,
                              void* d_out, int out_size, void* d_ws, size_t ws_size,
                              hipStream_t stream) {
    const float* x   = (const float*)d_in[0];
    const int*   idx = (const int*)d_in[1];
    const float* W0  = (const float*)d_in[2];
    const float* as0 = (const float*)d_in[3];
    const float* ad0 = (const float*)d_in[4];
    const float* b0  = (const float*)d_in[5];
    const float* W1  = (const float*)d_in[6];
    const float* as1 = (const float*)d_in[7];
    const float* ad1 = (const float*)d_in[8];
    const float* b1  = (const float*)d_in[9];
    const float* W2  = (const float*)d_in[10];
    const float* as2 = (const float*)d_in[11];
    const float* ad2 = (const float*)d_in[12];
    const float* b2  = (const float*)d_in[13];
    float* out = (float*)d_out;

    const int n    = in_sizes[0] / 128;   // 50000
    const int E    = in_sizes[1] / 2;     // 800000
    const int etot = E + n;

    char* p = (char*)d_ws;
    auto alloc = [&](size_t bytes) {
        char* r = p;
        p += (bytes + 255) & ~(size_t)255;
        return r;
    };
    int*    off   = (int*)alloc((size_t)(n + 1) * 4);
    int*    csr   = (int*)alloc((size_t)(etot + 8) * 4);   // +8 prefetch pad
    int*    ghist = (int*)alloc(256 * 4);                  // ghist+dhist:
    int*    dhist = (int*)alloc(256 * 4);                  // contiguous
    int*    goff  = (int*)alloc(257 * 4);
    int*    gcur  = (int*)alloc(256 * 4);
    int*    dcur  = (int*)alloc(256 * 4);
    int*    perm  = (int*)alloc((size_t)n * 4);
    float*  asbA  = (float*)alloc((size_t)n * 4 * 4);
    float*  adbA  = (float*)alloc((size_t)n * 4 * 4);
    float*  asbB  = (float*)alloc((size_t)n * 4 * 4);
    float*  adbB  = (float*)alloc((size_t)n * 4 * 4);
    __half* hA    = (__half*)alloc((size_t)n * 64 * 2);
    __half* hB    = (__half*)alloc((size_t)n * 64 * 2);
    unsigned long long* buf = (unsigned long long*)alloc((size_t)etot * 8);

    const int nb_l1 = (etot + L1_CHUNK - 1) / L1_CHUNK;  // 208
    const int nb_l2 = (n + 255) / 256;                   // 196
    const int nb_g  = (n + 15) / 16;                     // 3125

    // CSR build + degree-sorted permutation
    hipMemsetAsync(ghist, 0, 2 * 256 * 4, stream);       // ghist + dhist
    k_l1hist<<<nb_l1, 256, 0, stream>>>(idx, ghist, E, etot);
    k_scan256<<<1, 256, 0, stream>>>(ghist, goff, gcur);
    k_l1scatter<<<nb_l1, 256, 0, stream>>>(idx, gcur, buf, E, etot);
    k_l2build<<<nb_l2, 256, 0, stream>>>(buf, goff, off, csr, dhist, n, etot);
    k_degscan<<<1, 256, 0, stream>>>(dhist, dcur);
    k_permscatter<<<nb_l2, 256, 0, stream>>>(off, dcur, perm, n);

    // layer 0 GEMM: x(128) -> hA(fp16), logits A
    k_gemm_alpha<128, 4, 16><<<nb_g, 256, 0, stream>>>(x, W0, as0, ad0, hA, asbA, adbA, n);
    // agg0 (+b0, ELU) -> gemm1 -> hB(fp16), logits B
    k_agg_gemm<4, 4, 16><<<nb_g, 256, 0, stream>>>(hA, asbA, adbA, off, csr, perm, b0,
                                                   W1, as1, ad1, hB, asbB, adbB, n);
    // agg1 (+b1, ELU) -> gemm2 -> hA(fp16), logits A
    k_agg_gemm<4, 1, 64><<<nb_g, 256, 0, stream>>>(hB, asbB, adbB, off, csr, perm, b1,
                                                   W2, as2, ad2, hA, asbA, adbA, n);
    // agg2 (+b2) -> fp32 out
    k_agg_final<<<nb_g, 256, 0, stream>>>(hA, asbA, adbA, off, csr, perm, b2, out, n);
}